// Round 18
// baseline (853.422 us; speedup 1.0000x reference)
//
#include <hip/hip_runtime.h>

// STGAT round 18: gat_k G1/G2 projections -> MFMA (W-frag A-operand, xn/x2
// staged bf16 hi/lo with bank-safe padded rows); A2 exp dedup via P2 staging
// (8 exps/thread instead of 64, 8x wave duplication removed). A1 apply stays
// FMA (P1 staging would not fit LDS). traj/graph/dec identical to round 17.

#define OBS 8
#define FUT 12
#define NPED 64
#define HT_ 32
#define HG_ 32
#define NZ_ 8
#define HP_ 72
#define NGR 1024
#define NTOT (NGR * NPED)
#define AP2 80
#define EAP 72
#define XNP 56   // xn row stride (u16): 112B rows, 16B-aligned, 2-way banks
#define X2P 72   // x2 row stride (u16): 144B rows, 16B-aligned, 2-way banks
#define P2P 68   // P2 row stride (f32): 272B rows, 16B-aligned, 2-way banks

typedef __attribute__((ext_vector_type(8))) short short8_t;
typedef __attribute__((ext_vector_type(4))) float f32x4;
typedef unsigned short u16;

__device__ __forceinline__ float frcp(float x) { return __builtin_amdgcn_rcpf(x); }
__device__ __forceinline__ float sigf(float x) { return frcp(1.0f + __expf(-x)); }
__device__ __forceinline__ float tanh_(float x) {
    float e = __expf(2.0f * x);
    return 1.0f - 2.0f * frcp(e + 1.0f);
}
__device__ __forceinline__ float leaky(float x) { return (x > 0.0f) ? x : 0.2f * x; }
__device__ __forceinline__ u16 bhi(float v) {
    unsigned u = __float_as_uint(v);
    return (u16)((u + 0x7FFFu + ((u >> 16) & 1u)) >> 16);
}
__device__ __forceinline__ float bf2f(u16 h) { return __uint_as_float(((unsigned)h) << 16); }

// ====================== A: traj LSTM (MFMA, 2 barriers/t) =================
__global__ __launch_bounds__(512, 1)
void traj_lstm_k(const float* __restrict__ obs,
                 const float* __restrict__ h0,
                 const float* __restrict__ c0,
                 const float* __restrict__ w_ih,
                 const float* __restrict__ w_hh,
                 const float* __restrict__ b_ih,
                 const float* __restrict__ b_hh,
                 float* __restrict__ ws1,    // xn f32 [8][32][N]
                 float* __restrict__ wsT)    // raw h at t=7, [32][N]
{
    const int g    = blockIdx.x;
    const int lane = threadIdx.x & 63;
    const int wv   = __builtin_amdgcn_readfirstlane((int)(threadIdx.x >> 6));
    const int n    = g * NPED + lane;

    __shared__ __attribute__((aligned(16))) u16 ATh[64 * EAP], ATl[64 * EAP];

    const int pfrag = lane & 15, kg8 = (lane >> 4) * 8;
    const int pcol  = lane & 15;
    const int jg    = wv * 4 + (lane >> 4);

    short8_t wfhT[2], wflT[2];
    {
        int gp = wv * 16 + pfrag, j = gp >> 2, ty = gp & 3, orig = ty * 32 + j;
        #pragma unroll
        for (int kb = 0; kb < 2; ++kb) {
            short8_t fh, fl;
            #pragma unroll
            for (int jj = 0; jj < 8; ++jj) {
                int k = kb * 32 + (lane >> 4) * 8 + jj;
                float v;
                if (k < 32)       v = w_hh[orig * 32 + k];
                else if (k < 35)  v = w_ih[orig * 3 + (k - 32)];
                else if (k == 35) v = b_ih[orig] + b_hh[orig];
                else              v = 0.0f;
                u16 h = bhi(v);
                fh[jj] = (short)h;
                fl[jj] = (short)bhi(v - bf2f(h));
            }
            wfhT[kb] = fh;
            wflT[kb] = fl;
        }
    }
    #pragma unroll
    for (int r = 0; r < 4; ++r) {
        int j = wv * 4 + r;
        float vt = h0[(size_t)n * HT_ + j];
        u16 h = bhi(vt);
        ATh[lane * EAP + j] = h;  ATl[lane * EAP + j] = bhi(vt - bf2f(h));
    }
    if (wv == 0) {
        #pragma unroll
        for (int c = 0; c < 3; ++c) {
            float v = obs[((size_t)0 * NTOT + n) * 3 + c];
            u16 h = bhi(v);
            ATh[lane * EAP + 32 + c] = h;  ATl[lane * EAP + 32 + c] = bhi(v - bf2f(h));
        }
        ATh[lane * EAP + 35] = 0x3F80;  ATl[lane * EAP + 35] = 0;
    } else if (wv == 1) {
        for (int c = 36; c < 64; ++c) { ATh[lane * EAP + c] = 0; ATl[lane * EAP + c] = 0; }
    }
    float cT2[4];
    #pragma unroll
    for (int mb = 0; mb < 4; ++mb)
        cT2[mb] = c0[(size_t)(g * 64 + mb * 16 + pcol) * HT_ + jg];
    __syncthreads();

    for (int t = 0; t < OBS; ++t) {
        float h2[4];
        {
            f32x4 acc[4];
            #pragma unroll
            for (int mb = 0; mb < 4; ++mb) acc[mb] = (f32x4){0.f, 0.f, 0.f, 0.f};
            #pragma unroll
            for (int kb = 0; kb < 2; ++kb) {
                short8_t ah[4], al[4];
                #pragma unroll
                for (int mb = 0; mb < 4; ++mb) {
                    int off = (mb * 16 + pfrag) * EAP + kb * 32 + kg8;
                    ah[mb] = *(const short8_t*)&ATh[off];
                    al[mb] = *(const short8_t*)&ATl[off];
                }
                #pragma unroll
                for (int mb = 0; mb < 4; ++mb) {
                    acc[mb] = __builtin_amdgcn_mfma_f32_16x16x32_bf16(wfhT[kb], ah[mb], acc[mb], 0, 0, 0);
                    acc[mb] = __builtin_amdgcn_mfma_f32_16x16x32_bf16(wflT[kb], ah[mb], acc[mb], 0, 0, 0);
                    acc[mb] = __builtin_amdgcn_mfma_f32_16x16x32_bf16(wfhT[kb], al[mb], acc[mb], 0, 0, 0);
                }
            }
            #pragma unroll
            for (int mb = 0; mb < 4; ++mb) {
                float gi = acc[mb][0], gf = acc[mb][1];
                float gg = acc[mb][2], go = acc[mb][3];
                float c = sigf(gf) * cT2[mb] + sigf(gi) * tanh_(gg);
                cT2[mb] = c;
                h2[mb] = sigf(go) * tanh_(c);
            }
        }
        float sm = (h2[0] + h2[1]) + (h2[2] + h2[3]);
        float sq = (h2[0]*h2[0] + h2[1]*h2[1]) + (h2[2]*h2[2] + h2[3]*h2[3]);
        sm += __shfl_xor(sm, 1);  sq += __shfl_xor(sq, 1);
        sm += __shfl_xor(sm, 2);  sq += __shfl_xor(sq, 2);
        sm += __shfl_xor(sm, 4);  sq += __shfl_xor(sq, 4);
        sm += __shfl_xor(sm, 8);  sq += __shfl_xor(sq, 8);
        float mean = sm * (1.0f / 64.0f);
        float var  = sq * (1.0f / 64.0f) - mean * mean;
        float rstd = rsqrtf(var + 1e-5f);
        __syncthreads();   // B1
        #pragma unroll
        for (int mb = 0; mb < 4; ++mb) {
            int p = mb * 16 + pcol;
            u16 h = bhi(h2[mb]);
            ATh[p * EAP + jg] = h;  ATl[p * EAP + jg] = bhi(h2[mb] - bf2f(h));
            ws1[((size_t)t * 32 + jg) * NTOT + g * 64 + p] = (h2[mb] - mean) * rstd;
        }
        if (t == OBS - 1) {
            #pragma unroll
            for (int mb = 0; mb < 4; ++mb)
                wsT[(size_t)jg * NTOT + g * 64 + mb * 16 + pcol] = h2[mb];
        } else if (wv == 0) {
            #pragma unroll
            for (int c = 0; c < 3; ++c) {
                float v = obs[((size_t)(t + 1) * NTOT + n) * 3 + c];
                u16 h = bhi(v);
                ATh[lane * EAP + 32 + c] = h;  ATl[lane * EAP + 32 + c] = bhi(v - bf2f(h));
            }
        }
        __syncthreads();   // B2
    }
}

// ====================== B: GAT (MFMA projections, staged A2 exps) =========
__global__ __launch_bounds__(512, 2)
void gat_k(const float* __restrict__ ws1,
           const float* __restrict__ g1w,
           const float* __restrict__ g1as,
           const float* __restrict__ g1ad,
           const float* __restrict__ g1b,
           const float* __restrict__ g2w,
           const float* __restrict__ g2as,
           const float* __restrict__ g2ad,
           const float* __restrict__ g2b,
           float* __restrict__ ws2)
{
    const int t    = blockIdx.x >> 10;
    const int g    = blockIdx.x & 1023;
    const int lane = threadIdx.x & 63;
    const int wv   = __builtin_amdgcn_readfirstlane((int)(threadIdx.x >> 6));

    __shared__ __attribute__((aligned(16))) u16 xnh[64 * XNP], xnl[64 * XNP]; // [ped][k]
    __shared__ float hp1s[64 * 64];                                           // [o_all][ped]; hp2 = rows 0..31
    __shared__ __attribute__((aligned(16))) u16 x2h[64 * X2P], x2l[64 * X2P]; // [ped][k]
    __shared__ __attribute__((aligned(16))) float P2[64 * P2P];               // [i][m]
    __shared__ float s1f[256], d1f[256];    // [h][ped]
    __shared__ float sp2f[128], dp2f[128];  // [mb][ped]
    float* hp2 = hp1s;

    const int pfrag = lane & 15, kg8 = (lane >> 4) * 8;

    // ---- W fragments (A-operand rows; per-wave persistent) ----
    const int mb1 = wv >> 1;              // G1: head / o-block
    const int nb1 = (wv & 1) * 2;         // G1: first of two ped blocks
    short8_t w1h, w1l;
    {
        short8_t fh, fl;
        #pragma unroll
        for (int j = 0; j < 8; ++j) {
            int k = kg8 + j;
            float v = g1w[mb1 * 512 + k * 16 + pfrag];
            u16 h = bhi(v);
            fh[j] = (short)h;
            fl[j] = (short)bhi(v - bf2f(h));
        }
        w1h = fh; w1l = fl;
    }
    const int mb2g = wv >> 2, nb2g = wv & 3;   // G2 tile
    short8_t w2h[2], w2l[2];
    #pragma unroll
    for (int kb = 0; kb < 2; ++kb) {
        short8_t fh, fl;
        #pragma unroll
        for (int j = 0; j < 8; ++j) {
            int k = kb * 32 + kg8 + j;
            float v = g2w[k * 32 + mb2g * 16 + pfrag];
            u16 h = bhi(v);
            fh[j] = (short)h;
            fl[j] = (short)bhi(v - bf2f(h));
        }
        w2h[kb] = fh; w2l[kb] = fl;
    }

    // ---- stage xn (bf16 hi/lo, [ped][k]) ----
    #pragma unroll
    for (int r = 0; r < 4; ++r) {
        int f = wv * 4 + r;
        float v = ws1[((size_t)t * 32 + f) * NTOT + g * 64 + lane];
        u16 h = bhi(v);
        xnh[lane * XNP + f] = h;
        xnl[lane * XNP + f] = bhi(v - bf2f(h));
    }
    __syncthreads();   // B0

    // ===== G1 via MFMA: hp1[o_all][ped] + s1/d1 =====
    #pragma unroll
    for (int nbi = 0; nbi < 2; ++nbi) {
        int nb = nb1 + nbi;
        short8_t bh = *(const short8_t*)&xnh[(nb * 16 + pfrag) * XNP + kg8];
        short8_t bl = *(const short8_t*)&xnl[(nb * 16 + pfrag) * XNP + kg8];
        f32x4 acc = (f32x4){0.f, 0.f, 0.f, 0.f};
        acc = __builtin_amdgcn_mfma_f32_16x16x32_bf16(w1h, bh, acc, 0, 0, 0);
        acc = __builtin_amdgcn_mfma_f32_16x16x32_bf16(w1l, bh, acc, 0, 0, 0);
        acc = __builtin_amdgcn_mfma_f32_16x16x32_bf16(w1h, bl, acc, 0, 0, 0);
        float sp = 0.0f, dp = 0.0f;
        #pragma unroll
        for (int reg = 0; reg < 4; ++reg) {
            int o_in = (lane >> 4) * 4 + reg;
            hp1s[(mb1 * 16 + o_in) * 64 + nb * 16 + pfrag] = acc[reg];
            sp += acc[reg] * g1as[mb1 * 16 + o_in];
            dp += acc[reg] * g1ad[mb1 * 16 + o_in];
        }
        sp += __shfl_xor(sp, 16);  sp += __shfl_xor(sp, 32);
        dp += __shfl_xor(dp, 16);  dp += __shfl_xor(dp, 32);
        s1f[mb1 * 64 + nb * 16 + pfrag] = sp;   // 4 lanes write same value
        d1f[mb1 * 64 + nb * 16 + pfrag] = dp;
    }
    __syncthreads();   // B1

    // ===== A1: FMA apply + elu + inorm -> x2 (bf16 hi/lo) =====
    {
        const int h_ = wv >> 1;
        const int o0 = (wv & 1) * 8;
        const float sv   = s1f[h_ * 64 + lane];
        const float dtot = d1f[h_ * 64 + lane];
        float sum = 0.0f;
        float acc[8];
        #pragma unroll
        for (int q = 0; q < 8; ++q) acc[q] = 0.0f;
        #pragma unroll
        for (int m4 = 0; m4 < 16; ++m4) {
            float e0 = __expf(leaky(sv + __shfl(dtot, m4 * 4 + 0)));
            float e1 = __expf(leaky(sv + __shfl(dtot, m4 * 4 + 1)));
            float e2 = __expf(leaky(sv + __shfl(dtot, m4 * 4 + 2)));
            float e3 = __expf(leaky(sv + __shfl(dtot, m4 * 4 + 3)));
            sum += e0 + e1 + e2 + e3;
            #pragma unroll
            for (int q = 0; q < 8; ++q) {
                float4 hv = *reinterpret_cast<const float4*>(&hp1s[(h_ * 16 + o0 + q) * 64 + m4 * 4]);
                acc[q] += e0 * hv.x + e1 * hv.y + e2 * hv.z + e3 * hv.w;
            }
        }
        float rs = frcp(sum);
        #pragma unroll
        for (int q = 0; q < 8; ++q) {
            float v = acc[q] * rs + g1b[o0 + q];
            v = (v > 0.0f) ? v : (__expf(v) - 1.0f);
            float sm = v, sq = v * v;
            #pragma unroll
            for (int m = 1; m < 64; m <<= 1) { sm += __shfl_xor(sm, m); sq += __shfl_xor(sq, m); }
            float mean = sm * (1.0f / 64.0f);
            float var  = sq * (1.0f / 64.0f) - mean * mean;
            float vn = (v - mean) * rsqrtf(var + 1e-5f);
            int f = h_ * 16 + o0 + q;
            u16 hh = bhi(vn);
            x2h[lane * X2P + f] = hh;
            x2l[lane * X2P + f] = bhi(vn - bf2f(hh));
        }
    }
    __syncthreads();   // B2

    // ===== G2 via MFMA: hp2[o][ped] + s2/d2 partials =====
    {
        f32x4 acc = (f32x4){0.f, 0.f, 0.f, 0.f};
        #pragma unroll
        for (int kb = 0; kb < 2; ++kb) {
            short8_t bh = *(const short8_t*)&x2h[(nb2g * 16 + pfrag) * X2P + kb * 32 + kg8];
            short8_t bl = *(const short8_t*)&x2l[(nb2g * 16 + pfrag) * X2P + kb * 32 + kg8];
            acc = __builtin_amdgcn_mfma_f32_16x16x32_bf16(w2h[kb], bh, acc, 0, 0, 0);
            acc = __builtin_amdgcn_mfma_f32_16x16x32_bf16(w2l[kb], bh, acc, 0, 0, 0);
            acc = __builtin_amdgcn_mfma_f32_16x16x32_bf16(w2h[kb], bl, acc, 0, 0, 0);
        }
        float sp = 0.0f, dp = 0.0f;
        #pragma unroll
        for (int reg = 0; reg < 4; ++reg) {
            int o_all = mb2g * 16 + (lane >> 4) * 4 + reg;
            hp2[o_all * 64 + nb2g * 16 + pfrag] = acc[reg];
            sp += acc[reg] * g2as[o_all];
            dp += acc[reg] * g2ad[o_all];
        }
        sp += __shfl_xor(sp, 16);  sp += __shfl_xor(sp, 32);
        dp += __shfl_xor(dp, 16);  dp += __shfl_xor(dp, 32);
        sp2f[mb2g * 64 + nb2g * 16 + pfrag] = sp;
        dp2f[mb2g * 64 + nb2g * 16 + pfrag] = dp;
    }
    __syncthreads();   // B3

    // ===== P2 staging: wave wv computes rows [i=lane][m=wv*8..+8] =====
    const float sv2 = sp2f[lane] + sp2f[64 + lane];
    const float dt2 = dp2f[lane] + dp2f[64 + lane];
    {
        float e[8];
        #pragma unroll
        for (int k = 0; k < 8; ++k) {
            float dm = __shfl(dt2, wv * 8 + k);
            e[k] = __expf(leaky(sv2 + dm));
        }
        *reinterpret_cast<float4*>(&P2[lane * P2P + wv * 8 + 0]) = make_float4(e[0], e[1], e[2], e[3]);
        *reinterpret_cast<float4*>(&P2[lane * P2P + wv * 8 + 4]) = make_float4(e[4], e[5], e[6], e[7]);
    }
    __syncthreads();   // B4

    // ===== A2 apply (reads staged P2) -> gin =====
    {
        float sum = 0.0f;
        float acc[4];
        #pragma unroll
        for (int q = 0; q < 4; ++q) acc[q] = 0.0f;
        #pragma unroll
        for (int m4 = 0; m4 < 16; ++m4) {
            float4 pv = *reinterpret_cast<const float4*>(&P2[lane * P2P + m4 * 4]);
            sum += (pv.x + pv.y) + (pv.z + pv.w);
            #pragma unroll
            for (int q = 0; q < 4; ++q) {
                float4 hv = *reinterpret_cast<const float4*>(&hp2[(wv * 4 + q) * 64 + m4 * 4]);
                acc[q] += pv.x * hv.x + pv.y * hv.y + pv.z * hv.z + pv.w * hv.w;
            }
        }
        float rs = frcp(sum);
        #pragma unroll
        for (int q = 0; q < 4; ++q)
            ws2[((size_t)t * 32 + wv * 4 + q) * NTOT + g * 64 + lane] = acc[q] * rs + g2b[wv * 4 + q];
    }
}

// ====================== C: graph LSTM (MFMA, operand-swapped) =============
__global__ __launch_bounds__(512, 1)
void graph_lstm_k(const float* __restrict__ ws2,
                  const float* __restrict__ graph_h0,
                  const float* __restrict__ graph_c0,
                  const float* __restrict__ w_ih_g,
                  const float* __restrict__ w_hh_g,
                  const float* __restrict__ b_ih_g,
                  const float* __restrict__ b_hh_g,
                  float* __restrict__ wsG)
{
    const int g    = blockIdx.x;
    const int lane = threadIdx.x & 63;
    const int wv   = __builtin_amdgcn_readfirstlane((int)(threadIdx.x >> 6));
    const int n    = g * NPED + lane;

    __shared__ __attribute__((aligned(16))) u16 AGh[64 * EAP], AGl[64 * EAP];
    __shared__ float biasg[128];

    const int pfrag = lane & 15, kg8 = (lane >> 4) * 8;
    const int pcol = lane & 15;
    const int jg   = wv * 4 + (lane >> 4);

    short8_t wfhG[2], wflG[2];
    {
        int gp = wv * 16 + pfrag, j = gp >> 2, ty = gp & 3, orig = ty * 32 + j;
        #pragma unroll
        for (int kb = 0; kb < 2; ++kb) {
            short8_t fhG, flG;
            #pragma unroll
            for (int jj = 0; jj < 8; ++jj) {
                int k = kb * 32 + (lane >> 4) * 8 + jj;
                float vG = (k < 32) ? w_ih_g[orig * 32 + k] : w_hh_g[orig * 32 + (k - 32)];
                u16 hG = bhi(vG); fhG[jj] = (short)hG; flG[jj] = (short)bhi(vG - bf2f(hG));
            }
            wfhG[kb] = fhG; wflG[kb] = flG;
        }
    }
    #pragma unroll
    for (int r = 0; r < 4; ++r) {
        int j = wv * 4 + r;
        float vg = graph_h0[(size_t)n * HG_ + j];
        u16 hg = bhi(vg);
        AGh[lane * EAP + 32 + j] = hg;  AGl[lane * EAP + 32 + j] = bhi(vg - bf2f(hg));
    }
    float cG2[4];
    #pragma unroll
    for (int mb = 0; mb < 4; ++mb)
        cG2[mb] = graph_c0[(size_t)(g * 64 + mb * 16 + pcol) * HG_ + jg];
    if (threadIdx.x < 128) biasg[threadIdx.x] = b_ih_g[threadIdx.x] + b_hh_g[threadIdx.x];

    for (int t = 0; t < OBS; ++t) {
        #pragma unroll
        for (int r = 0; r < 4; ++r) {
            int f = wv * 4 + r;
            float v = ws2[((size_t)t * 32 + f) * NTOT + g * 64 + lane];
            u16 h = bhi(v);
            AGh[lane * EAP + f] = h;  AGl[lane * EAP + f] = bhi(v - bf2f(h));
        }
        __syncthreads();   // B1
        float h2G[4];
        {
            f32x4 acc[4];
            #pragma unroll
            for (int mb = 0; mb < 4; ++mb) acc[mb] = (f32x4){0.f, 0.f, 0.f, 0.f};
            #pragma unroll
            for (int kb = 0; kb < 2; ++kb) {
                short8_t ah[4], al[4];
                #pragma unroll
                for (int mb = 0; mb < 4; ++mb) {
                    int off = (mb * 16 + pfrag) * EAP + kb * 32 + kg8;
                    ah[mb] = *(const short8_t*)&AGh[off];
                    al[mb] = *(const short8_t*)&AGl[off];
                }
                #pragma unroll
                for (int mb = 0; mb < 4; ++mb) {
                    acc[mb] = __builtin_amdgcn_mfma_f32_16x16x32_bf16(wfhG[kb], ah[mb], acc[mb], 0, 0, 0);
                    acc[mb] = __builtin_amdgcn_mfma_f32_16x16x32_bf16(wflG[kb], ah[mb], acc[mb], 0, 0, 0);
                    acc[mb] = __builtin_amdgcn_mfma_f32_16x16x32_bf16(wfhG[kb], al[mb], acc[mb], 0, 0, 0);
                }
            }
            const float bI = biasg[jg], bF = biasg[32 + jg], bG = biasg[64 + jg], bO = biasg[96 + jg];
            #pragma unroll
            for (int mb = 0; mb < 4; ++mb) {
                float gi = acc[mb][0] + bI, gf = acc[mb][1] + bF;
                float gg = acc[mb][2] + bG, go = acc[mb][3] + bO;
                float c = sigf(gf) * cG2[mb] + sigf(gi) * tanh_(gg);
                cG2[mb] = c;
                h2G[mb] = sigf(go) * tanh_(c);
            }
        }
        __syncthreads();   // B2
        #pragma unroll
        for (int mb = 0; mb < 4; ++mb) {
            int p = mb * 16 + pcol;
            u16 h = bhi(h2G[mb]);
            AGh[p * EAP + 32 + jg] = h;  AGl[p * EAP + 32 + jg] = bhi(h2G[mb] - bf2f(h));
        }
        if (t == OBS - 1) {
            #pragma unroll
            for (int mb = 0; mb < 4; ++mb)
                wsG[(size_t)jg * NTOT + g * 64 + mb * 16 + pcol] = h2G[mb];
        }
    }
}

// ==== D: decoder (round-15: balanced tiles, 2 barriers/step) ==============
__global__ __launch_bounds__(512, 1)
void stgat_dec(const float* __restrict__ obs,
               const float* __restrict__ zin,
               const float* __restrict__ w_ih_p,
               const float* __restrict__ w_hh_p,
               const float* __restrict__ b_ih_p,
               const float* __restrict__ b_hh_p,
               const float* __restrict__ w_out,
               const float* __restrict__ b_out,
               const float* __restrict__ wsT,
               const float* __restrict__ wsG,
               float* __restrict__ out)
{
    const int g    = blockIdx.x;
    const int lane = threadIdx.x & 63;
    const int wv   = __builtin_amdgcn_readfirstlane((int)(threadIdx.x >> 6));
    const int n    = g * NPED + lane;

    __shared__ __attribute__((aligned(16))) u16 Apk[2 * 64 * AP2 + 16];
    __shared__ __attribute__((aligned(16))) short8_t WloS[18 * 3 * 64];
    __shared__ float red0[512], red1[512];
    u16* AhiA = Apk;
    u16* AhiB = Apk + 64 * AP2;

    const int pfrag = lane & 15, kgrp = (lane >> 4) * 8;
    const int pcol  = lane & 15;
    const int mb2   = wv & 3;
    const int nb2   = 16 + (wv >> 2);

    short8_t wfh[3][3];
    {
        const int col = lane & 15, lb = lane >> 4;
        #pragma unroll
        for (int s = 0; s < 3; ++s) {
            int nb = (s == 2) ? nb2 : (wv + 8 * s);
            int gp = nb * 16 + col;
            int j = gp >> 2, ty = gp & 3;
            int orig = ty * HP_ + j;
            #pragma unroll
            for (int kb = 0; kb < 3; ++kb) {
                short8_t fh, fl;
                #pragma unroll
                for (int jj = 0; jj < 8; ++jj) {
                    int k = kb * 32 + lb * 8 + jj;
                    float v;
                    if (k < 72)       v = w_hh_p[orig * HP_ + k];
                    else if (k == 72) v = w_ih_p[orig * 2 + 0];
                    else if (k == 73) v = w_ih_p[orig * 2 + 1];
                    else if (k == 74) v = b_ih_p[orig] + b_hh_p[orig];
                    else              v = 0.0f;
                    u16 hb = bhi(v);
                    fh[jj] = (short)hb;
                    fl[jj] = (short)bhi(v - bf2f(hb));
                }
                wfh[s][kb] = fh;
                if (s < 2 || (wv & 3) == 0)
                    WloS[(nb * 3 + kb) * 64 + lane] = fl;
            }
        }
    }
    float wo0[3], wo1[3];
    #pragma unroll
    for (int s = 0; s < 3; ++s) {
        int nb = (s == 2) ? nb2 : (wv + 8 * s);
        int j = nb * 4 + (lane >> 4);
        wo0[s] = w_out[j];
        wo1[s] = w_out[HP_ + j];
    }
    const float bo0 = b_out[0], bo1 = b_out[1];

    {
        float px0 = obs[(7 * NTOT + n) * 3 + 0];
        float px1 = obs[(7 * NTOT + n) * 3 + 1];
        #pragma unroll
        for (int kk = 0; kk < 12; ++kk) {
            int k = wv + kk * 8;
            if (k < AP2) {
                float va, vb;
                if (k < 32)       { va = wsT[(size_t)k * NTOT + n];            vb = 0.0f; }
                else if (k < 64)  { va = vb = wsG[(size_t)(k - 32) * NTOT + n]; }
                else if (k < 72)  { va = vb = zin[g * NZ_ + (k - 64)]; }
                else if (k == 72) { va = vb = px0; }
                else if (k == 73) { va = vb = px1; }
                else if (k == 74) { va = vb = 1.0f; }
                else              { va = vb = 0.0f; }
                AhiA[lane * AP2 + k] = bhi(va);
                AhiB[lane * AP2 + k] = bhi(vb);
            }
        }
        if (wv == 0 && lane < 16) Apk[2 * 64 * AP2 + lane] = 0;   // guard
    }
    __syncthreads();

    float cstA[2][4], cstB[2][4], cstA2 = 0.f, cstB2 = 0.f;
    #pragma unroll
    for (int s = 0; s < 2; ++s)
        #pragma unroll
        for (int mb = 0; mb < 4; ++mb) { cstA[s][mb] = 0.0f; cstB[s][mb] = 0.0f; }

    for (int st = 0; st < FUT; ++st) {
        float h2A[2][4], h2B[2][4], h2A2, h2B2;
        // ---- cell A ----
        {
            f32x4 acc[2][4];
            f32x4 acc2 = (f32x4){0.f, 0.f, 0.f, 0.f};
            #pragma unroll
            for (int s = 0; s < 2; ++s)
                #pragma unroll
                for (int mb = 0; mb < 4; ++mb) acc[s][mb] = (f32x4){0.f, 0.f, 0.f, 0.f};
            #pragma unroll
            for (int kb = 0; kb < 3; ++kb) {
                short8_t ah[4];
                #pragma unroll
                for (int mb = 0; mb < 4; ++mb) {
                    int off = (mb * 16 + pfrag) * AP2 + kb * 32 + kgrp;
                    ah[mb] = *(const short8_t*)&AhiA[off];
                }
                #pragma unroll
                for (int s = 0; s < 2; ++s) {
                    int nb = wv + 8 * s;
                    short8_t wl = WloS[(nb * 3 + kb) * 64 + lane];
                    #pragma unroll
                    for (int mb = 0; mb < 4; ++mb) {
                        acc[s][mb] = __builtin_amdgcn_mfma_f32_16x16x32_bf16(wfh[s][kb], ah[mb], acc[s][mb], 0, 0, 0);
                        acc[s][mb] = __builtin_amdgcn_mfma_f32_16x16x32_bf16(wl,         ah[mb], acc[s][mb], 0, 0, 0);
                    }
                }
                short8_t ah2 = *(const short8_t*)&AhiA[(mb2 * 16 + pfrag) * AP2 + kb * 32 + kgrp];
                short8_t wl2 = WloS[(nb2 * 3 + kb) * 64 + lane];
                acc2 = __builtin_amdgcn_mfma_f32_16x16x32_bf16(wfh[2][kb], ah2, acc2, 0, 0, 0);
                acc2 = __builtin_amdgcn_mfma_f32_16x16x32_bf16(wl2,        ah2, acc2, 0, 0, 0);
            }
            #pragma unroll
            for (int s = 0; s < 2; ++s)
                #pragma unroll
                for (int mb = 0; mb < 4; ++mb) {
                    float gi = acc[s][mb][0], gf = acc[s][mb][1];
                    float gg = acc[s][mb][2], go = acc[s][mb][3];
                    float c = sigf(gf) * cstA[s][mb] + sigf(gi) * tanh_(gg);
                    cstA[s][mb] = c;
                    h2A[s][mb] = sigf(go) * tanh_(c);
                }
            {
                float gi = acc2[0], gf = acc2[1], gg = acc2[2], go = acc2[3];
                float c = sigf(gf) * cstA2 + sigf(gi) * tanh_(gg);
                cstA2 = c;
                h2A2 = sigf(go) * tanh_(c);
            }
        }
        // ---- cell B ----
        {
            f32x4 acc[2][4];
            f32x4 acc2 = (f32x4){0.f, 0.f, 0.f, 0.f};
            #pragma unroll
            for (int s = 0; s < 2; ++s)
                #pragma unroll
                for (int mb = 0; mb < 4; ++mb) acc[s][mb] = (f32x4){0.f, 0.f, 0.f, 0.f};
            #pragma unroll
            for (int kb = 0; kb < 3; ++kb) {
                short8_t bh[4];
                #pragma unroll
                for (int mb = 0; mb < 4; ++mb) {
                    int off = (mb * 16 + pfrag) * AP2 + kb * 32 + kgrp;
                    bh[mb] = *(const short8_t*)&AhiB[off];
                }
                #pragma unroll
                for (int s = 0; s < 2; ++s) {
                    int nb = wv + 8 * s;
                    short8_t wl = WloS[(nb * 3 + kb) * 64 + lane];
                    #pragma unroll
                    for (int mb = 0; mb < 4; ++mb) {
                        acc[s][mb] = __builtin_amdgcn_mfma_f32_16x16x32_bf16(wfh[s][kb], bh[mb], acc[s][mb], 0, 0, 0);
                        acc[s][mb] = __builtin_amdgcn_mfma_f32_16x16x32_bf16(wl,         bh[mb], acc[s][mb], 0, 0, 0);
                    }
                }
                short8_t bh2 = *(const short8_t*)&AhiB[(mb2 * 16 + pfrag) * AP2 + kb * 32 + kgrp];
                short8_t wl2 = WloS[(nb2 * 3 + kb) * 64 + lane];
                acc2 = __builtin_amdgcn_mfma_f32_16x16x32_bf16(wfh[2][kb], bh2, acc2, 0, 0, 0);
                acc2 = __builtin_amdgcn_mfma_f32_16x16x32_bf16(wl2,        bh2, acc2, 0, 0, 0);
            }
            #pragma unroll
            for (int s = 0; s < 2; ++s)
                #pragma unroll
                for (int mb = 0; mb < 4; ++mb) {
                    float gi = acc[s][mb][0], gf = acc[s][mb][1];
                    float gg = acc[s][mb][2], go = acc[s][mb][3];
                    float c = sigf(gf) * cstB[s][mb] + sigf(gi) * tanh_(gg);
                    cstB[s][mb] = c;
                    h2B[s][mb] = sigf(go) * tanh_(c);
                }
            {
                float gi = acc2[0], gf = acc2[1], gg = acc2[2], go = acc2[3];
                float c = sigf(gf) * cstB2 + sigf(gi) * tanh_(gg);
                cstB2 = c;
                h2B2 = sigf(go) * tanh_(c);
            }
        }
        // ---- register partial dot + j-reduction + PRE-B1 red stash ----
        float po0[4] = {0.f, 0.f, 0.f, 0.f}, po1[4] = {0.f, 0.f, 0.f, 0.f};
        #pragma unroll
        for (int s = 0; s < 2; ++s)
            #pragma unroll
            for (int mb = 0; mb < 4; ++mb) {
                float dh = h2A[s][mb] - h2B[s][mb];
                po0[mb] += wo0[s] * dh;
                po1[mb] += wo1[s] * dh;
            }
        {
            float dh2 = h2A2 - h2B2;
            float c0 = wo0[2] * dh2, c1 = wo1[2] * dh2;
            #pragma unroll
            for (int mb = 0; mb < 4; ++mb) {
                po0[mb] += (mb == mb2) ? c0 : 0.0f;
                po1[mb] += (mb == mb2) ? c1 : 0.0f;
            }
        }
        #pragma unroll
        for (int mb = 0; mb < 4; ++mb) {
            po0[mb] += __shfl_xor(po0[mb], 16);  po0[mb] += __shfl_xor(po0[mb], 32);
            po1[mb] += __shfl_xor(po1[mb], 16);  po1[mb] += __shfl_xor(po1[mb], 32);
        }
        if ((lane >> 4) == 0) {
            #pragma unroll
            for (int mb = 0; mb < 4; ++mb) {
                red0[wv * 64 + mb * 16 + lane] = po0[mb];
                red1[wv * 64 + mb * 16 + lane] = po1[mb];
            }
        }
        __syncthreads();   // B1: GEMM reads done; red visible
        #pragma unroll
        for (int s = 0; s < 2; ++s) {
            int j = (wv + 8 * s) * 4 + (lane >> 4);
            #pragma unroll
            for (int mb = 0; mb < 4; ++mb) {
                int p = mb * 16 + pcol;
                AhiA[p * AP2 + j] = bhi(h2A[s][mb]);
                AhiB[p * AP2 + j] = bhi(h2B[s][mb]);
            }
        }
        {
            int j2 = nb2 * 4 + (lane >> 4);
            int p2 = mb2 * 16 + pcol;
            AhiA[p2 * AP2 + j2] = bhi(h2A2);
            AhiB[p2 * AP2 + j2] = bhi(h2B2);
        }
        if (wv == 0) {
            float o0 = bo0, o1 = bo1;
            #pragma unroll
            for (int w = 0; w < 8; ++w) { o0 += red0[w * 64 + lane]; o1 += red1[w * 64 + lane]; }
            *reinterpret_cast<float2*>(&out[(size_t)(st * NTOT + n) * 2]) = make_float2(o0, o1);
            u16 h0_ = bhi(o0);
            u16 h1  = bhi(o1);
            AhiA[lane * AP2 + 72] = h0_;  AhiB[lane * AP2 + 72] = h0_;
            AhiA[lane * AP2 + 73] = h1;   AhiB[lane * AP2 + 73] = h1;
        }
        __syncthreads();   // B2: h2 + px visible
    }
}

extern "C" void kernel_launch(void* const* d_in, const int* in_sizes, int n_in,
                              void* d_out, int out_size, void* d_ws, size_t ws_size,
                              hipStream_t stream) {
    (void)in_sizes; (void)n_in; (void)out_size; (void)ws_size;
    const size_t NF = (size_t)OBS * 32 * NTOT;
    float* ws1 = (float*)d_ws;
    float* ws2 = ws1 + NF;
    float* wsT = ws2 + NF;
    float* wsG = wsT + (size_t)32 * NTOT;

    traj_lstm_k<<<dim3(NGR), dim3(512), 0, stream>>>(
        (const float*)d_in[0], (const float*)d_in[2], (const float*)d_in[3],
        (const float*)d_in[6], (const float*)d_in[7], (const float*)d_in[8], (const float*)d_in[9],
        ws1, wsT);

    gat_k<<<dim3(OBS * NGR), dim3(512), 0, stream>>>(
        ws1,
        (const float*)d_in[10], (const float*)d_in[11], (const float*)d_in[12], (const float*)d_in[13],
        (const float*)d_in[14], (const float*)d_in[15], (const float*)d_in[16], (const float*)d_in[17],
        ws2);

    graph_lstm_k<<<dim3(NGR), dim3(512), 0, stream>>>(
        ws2, (const float*)d_in[4], (const float*)d_in[5],
        (const float*)d_in[18], (const float*)d_in[19], (const float*)d_in[20], (const float*)d_in[21],
        wsG);

    stgat_dec<<<dim3(NGR), dim3(512), 0, stream>>>(
        (const float*)d_in[0], (const float*)d_in[1],
        (const float*)d_in[22], (const float*)d_in[23],
        (const float*)d_in[24], (const float*)d_in[25],
        (const float*)d_in[26], (const float*)d_in[27],
        wsT, wsG, (float*)d_out);
}

// Round 19
// 651.164 us; speedup vs baseline: 1.3106x; 1.3106x over previous
//
#include <hip/hip_runtime.h>

// STGAT round 19: revert gat_k to round-17 (MFMA-gat lost 2-block occupancy:
// 40.9->69.6KB LDS, +1 barrier, bank conflicts; 376->576us). One change:
// gat launch_bounds (512,2)->(512,3) — 56 VGPR fits the ~85 cap, 3x40.9KB LDS
// fits 160KB -> third co-resident block pushes VALU issue 85%->~95%.
// traj/graph/dec identical to round 17.

#define OBS 8
#define FUT 12
#define NPED 64
#define HT_ 32
#define HG_ 32
#define NZ_ 8
#define HP_ 72
#define NGR 1024
#define NTOT (NGR * NPED)
#define AP2 80
#define EAP 72

typedef __attribute__((ext_vector_type(8))) short short8_t;
typedef __attribute__((ext_vector_type(4))) float f32x4;
typedef unsigned short u16;

__device__ __forceinline__ float frcp(float x) { return __builtin_amdgcn_rcpf(x); }
__device__ __forceinline__ float sigf(float x) { return frcp(1.0f + __expf(-x)); }
__device__ __forceinline__ float tanh_(float x) {
    float e = __expf(2.0f * x);
    return 1.0f - 2.0f * frcp(e + 1.0f);
}
__device__ __forceinline__ float leaky(float x) { return (x > 0.0f) ? x : 0.2f * x; }
__device__ __forceinline__ u16 bhi(float v) {
    unsigned u = __float_as_uint(v);
    return (u16)((u + 0x7FFFu + ((u >> 16) & 1u)) >> 16);
}
__device__ __forceinline__ float bf2f(u16 h) { return __uint_as_float(((unsigned)h) << 16); }

// ====================== A: traj LSTM (MFMA, 2 barriers/t) =================
__global__ __launch_bounds__(512, 1)
void traj_lstm_k(const float* __restrict__ obs,
                 const float* __restrict__ h0,
                 const float* __restrict__ c0,
                 const float* __restrict__ w_ih,
                 const float* __restrict__ w_hh,
                 const float* __restrict__ b_ih,
                 const float* __restrict__ b_hh,
                 float* __restrict__ ws1,    // xn f32 [8][32][N]
                 float* __restrict__ wsT)    // raw h at t=7, [32][N]
{
    const int g    = blockIdx.x;
    const int lane = threadIdx.x & 63;
    const int wv   = __builtin_amdgcn_readfirstlane((int)(threadIdx.x >> 6));
    const int n    = g * NPED + lane;

    __shared__ __attribute__((aligned(16))) u16 ATh[64 * EAP], ATl[64 * EAP];

    const int pfrag = lane & 15, kg8 = (lane >> 4) * 8;
    const int pcol  = lane & 15;
    const int jg    = wv * 4 + (lane >> 4);

    short8_t wfhT[2], wflT[2];
    {
        int gp = wv * 16 + pfrag, j = gp >> 2, ty = gp & 3, orig = ty * 32 + j;
        #pragma unroll
        for (int kb = 0; kb < 2; ++kb) {
            short8_t fh, fl;
            #pragma unroll
            for (int jj = 0; jj < 8; ++jj) {
                int k = kb * 32 + (lane >> 4) * 8 + jj;
                float v;
                if (k < 32)       v = w_hh[orig * 32 + k];
                else if (k < 35)  v = w_ih[orig * 3 + (k - 32)];
                else if (k == 35) v = b_ih[orig] + b_hh[orig];
                else              v = 0.0f;
                u16 h = bhi(v);
                fh[jj] = (short)h;
                fl[jj] = (short)bhi(v - bf2f(h));
            }
            wfhT[kb] = fh;
            wflT[kb] = fl;
        }
    }
    #pragma unroll
    for (int r = 0; r < 4; ++r) {
        int j = wv * 4 + r;
        float vt = h0[(size_t)n * HT_ + j];
        u16 h = bhi(vt);
        ATh[lane * EAP + j] = h;  ATl[lane * EAP + j] = bhi(vt - bf2f(h));
    }
    if (wv == 0) {
        #pragma unroll
        for (int c = 0; c < 3; ++c) {
            float v = obs[((size_t)0 * NTOT + n) * 3 + c];
            u16 h = bhi(v);
            ATh[lane * EAP + 32 + c] = h;  ATl[lane * EAP + 32 + c] = bhi(v - bf2f(h));
        }
        ATh[lane * EAP + 35] = 0x3F80;  ATl[lane * EAP + 35] = 0;
    } else if (wv == 1) {
        for (int c = 36; c < 64; ++c) { ATh[lane * EAP + c] = 0; ATl[lane * EAP + c] = 0; }
    }
    float cT2[4];
    #pragma unroll
    for (int mb = 0; mb < 4; ++mb)
        cT2[mb] = c0[(size_t)(g * 64 + mb * 16 + pcol) * HT_ + jg];
    __syncthreads();

    for (int t = 0; t < OBS; ++t) {
        float h2[4];
        {
            f32x4 acc[4];
            #pragma unroll
            for (int mb = 0; mb < 4; ++mb) acc[mb] = (f32x4){0.f, 0.f, 0.f, 0.f};
            #pragma unroll
            for (int kb = 0; kb < 2; ++kb) {
                short8_t ah[4], al[4];
                #pragma unroll
                for (int mb = 0; mb < 4; ++mb) {
                    int off = (mb * 16 + pfrag) * EAP + kb * 32 + kg8;
                    ah[mb] = *(const short8_t*)&ATh[off];
                    al[mb] = *(const short8_t*)&ATl[off];
                }
                #pragma unroll
                for (int mb = 0; mb < 4; ++mb) {
                    acc[mb] = __builtin_amdgcn_mfma_f32_16x16x32_bf16(wfhT[kb], ah[mb], acc[mb], 0, 0, 0);
                    acc[mb] = __builtin_amdgcn_mfma_f32_16x16x32_bf16(wflT[kb], ah[mb], acc[mb], 0, 0, 0);
                    acc[mb] = __builtin_amdgcn_mfma_f32_16x16x32_bf16(wfhT[kb], al[mb], acc[mb], 0, 0, 0);
                }
            }
            #pragma unroll
            for (int mb = 0; mb < 4; ++mb) {
                float gi = acc[mb][0], gf = acc[mb][1];
                float gg = acc[mb][2], go = acc[mb][3];
                float c = sigf(gf) * cT2[mb] + sigf(gi) * tanh_(gg);
                cT2[mb] = c;
                h2[mb] = sigf(go) * tanh_(c);
            }
        }
        float sm = (h2[0] + h2[1]) + (h2[2] + h2[3]);
        float sq = (h2[0]*h2[0] + h2[1]*h2[1]) + (h2[2]*h2[2] + h2[3]*h2[3]);
        sm += __shfl_xor(sm, 1);  sq += __shfl_xor(sq, 1);
        sm += __shfl_xor(sm, 2);  sq += __shfl_xor(sq, 2);
        sm += __shfl_xor(sm, 4);  sq += __shfl_xor(sq, 4);
        sm += __shfl_xor(sm, 8);  sq += __shfl_xor(sq, 8);
        float mean = sm * (1.0f / 64.0f);
        float var  = sq * (1.0f / 64.0f) - mean * mean;
        float rstd = rsqrtf(var + 1e-5f);
        __syncthreads();   // B1
        #pragma unroll
        for (int mb = 0; mb < 4; ++mb) {
            int p = mb * 16 + pcol;
            u16 h = bhi(h2[mb]);
            ATh[p * EAP + jg] = h;  ATl[p * EAP + jg] = bhi(h2[mb] - bf2f(h));
            ws1[((size_t)t * 32 + jg) * NTOT + g * 64 + p] = (h2[mb] - mean) * rstd;
        }
        if (t == OBS - 1) {
            #pragma unroll
            for (int mb = 0; mb < 4; ++mb)
                wsT[(size_t)jg * NTOT + g * 64 + mb * 16 + pcol] = h2[mb];
        } else if (wv == 0) {
            #pragma unroll
            for (int c = 0; c < 3; ++c) {
                float v = obs[((size_t)(t + 1) * NTOT + n) * 3 + c];
                u16 h = bhi(v);
                ATh[lane * EAP + 32 + c] = h;  ATl[lane * EAP + 32 + c] = bhi(v - bf2f(h));
            }
        }
        __syncthreads();   // B2
    }
}

// ====================== B: GAT, one block per (t,g) =======================
__global__ __launch_bounds__(512, 3)
void gat_k(const float* __restrict__ ws1,
           const float* __restrict__ g1w,
           const float* __restrict__ g1as,
           const float* __restrict__ g1ad,
           const float* __restrict__ g1b,
           const float* __restrict__ g2w,
           const float* __restrict__ g2as,
           const float* __restrict__ g2ad,
           const float* __restrict__ g2b,
           float* __restrict__ ws2)
{
    const int t    = blockIdx.x >> 10;
    const int g    = blockIdx.x & 1023;
    const int lane = threadIdx.x & 63;
    const int wv   = __builtin_amdgcn_readfirstlane((int)(threadIdx.x >> 6));

    __shared__ float hp1s[4096];
    __shared__ float xnx[4096];
    __shared__ float sp1s[512], dp1s[512], sp2s[512], dp2s[512];
    float* xn  = xnx;
    float* x2  = xnx;
    float* hp2 = hp1s;

    #pragma unroll
    for (int r = 0; r < 4; ++r) {
        int f = wv * 4 + r;
        xn[f * 64 + lane] = ws1[((size_t)t * 32 + f) * NTOT + g * 64 + lane];
    }
    __syncthreads();
    {
        const int h_ = wv >> 1;
        const int o0 = (wv & 1) * 8;
        float acc[8];
        #pragma unroll
        for (int q = 0; q < 8; ++q) acc[q] = 0.0f;
        for (int k8 = 0; k8 < 4; ++k8) {
            float xk[8];
            #pragma unroll
            for (int i = 0; i < 8; ++i) xk[i] = xn[(k8 * 8 + i) * 64 + lane];
            #pragma unroll
            for (int i = 0; i < 8; ++i)
                #pragma unroll
                for (int q = 0; q < 8; ++q)
                    acc[q] += g1w[h_ * 512 + (k8 * 8 + i) * 16 + o0 + q] * xk[i];
        }
        float ps = 0.0f, pd = 0.0f;
        #pragma unroll
        for (int q = 0; q < 8; ++q) {
            hp1s[(h_ * 16 + o0 + q) * 64 + lane] = acc[q];
            ps += acc[q] * g1as[h_ * 16 + o0 + q];
            pd += acc[q] * g1ad[h_ * 16 + o0 + q];
        }
        sp1s[((wv & 1) * 4 + h_) * 64 + lane] = ps;
        dp1s[((wv & 1) * 4 + h_) * 64 + lane] = pd;
    }
    __syncthreads();
    {
        const int h_ = wv >> 1;
        const int o0 = (wv & 1) * 8;
        const float sv   = sp1s[h_ * 64 + lane] + sp1s[(4 + h_) * 64 + lane];
        const float dtot = dp1s[h_ * 64 + lane] + dp1s[(4 + h_) * 64 + lane];
        float sum = 0.0f;
        float acc[8];
        #pragma unroll
        for (int q = 0; q < 8; ++q) acc[q] = 0.0f;
        #pragma unroll
        for (int m4 = 0; m4 < 16; ++m4) {
            float e0 = __expf(leaky(sv + __shfl(dtot, m4 * 4 + 0)));
            float e1 = __expf(leaky(sv + __shfl(dtot, m4 * 4 + 1)));
            float e2 = __expf(leaky(sv + __shfl(dtot, m4 * 4 + 2)));
            float e3 = __expf(leaky(sv + __shfl(dtot, m4 * 4 + 3)));
            sum += e0 + e1 + e2 + e3;
            #pragma unroll
            for (int q = 0; q < 8; ++q) {
                float4 hv = *reinterpret_cast<const float4*>(&hp1s[(h_ * 16 + o0 + q) * 64 + m4 * 4]);
                acc[q] += e0 * hv.x + e1 * hv.y + e2 * hv.z + e3 * hv.w;
            }
        }
        float rs = frcp(sum);
        #pragma unroll
        for (int q = 0; q < 8; ++q) {
            float v = acc[q] * rs + g1b[o0 + q];
            v = (v > 0.0f) ? v : (__expf(v) - 1.0f);
            float sm = v, sq = v * v;
            #pragma unroll
            for (int m = 1; m < 64; m <<= 1) { sm += __shfl_xor(sm, m); sq += __shfl_xor(sq, m); }
            float mean = sm * (1.0f / 64.0f);
            float var  = sq * (1.0f / 64.0f) - mean * mean;
            x2[(h_ * 16 + o0 + q) * 64 + lane] = (v - mean) * rsqrtf(var + 1e-5f);
        }
    }
    __syncthreads();
    {
        float acc[4];
        #pragma unroll
        for (int q = 0; q < 4; ++q) acc[q] = 0.0f;
        for (int k8 = 0; k8 < 8; ++k8) {
            float xk[8];
            #pragma unroll
            for (int i = 0; i < 8; ++i) xk[i] = x2[(k8 * 8 + i) * 64 + lane];
            #pragma unroll
            for (int i = 0; i < 8; ++i)
                #pragma unroll
                for (int q = 0; q < 4; ++q)
                    acc[q] += g2w[(k8 * 8 + i) * 32 + wv * 4 + q] * xk[i];
        }
        float ps = 0.0f, pd = 0.0f;
        #pragma unroll
        for (int q = 0; q < 4; ++q) {
            hp2[(wv * 4 + q) * 64 + lane] = acc[q];
            ps += acc[q] * g2as[wv * 4 + q];
            pd += acc[q] * g2ad[wv * 4 + q];
        }
        sp2s[wv * 64 + lane] = ps;
        dp2s[wv * 64 + lane] = pd;
    }
    __syncthreads();
    {
        float sv = 0.0f, dtot = 0.0f;
        #pragma unroll
        for (int w = 0; w < 8; ++w) { sv += sp2s[w * 64 + lane]; dtot += dp2s[w * 64 + lane]; }
        float sum = 0.0f;
        float acc[4];
        #pragma unroll
        for (int q = 0; q < 4; ++q) acc[q] = 0.0f;
        #pragma unroll
        for (int m4 = 0; m4 < 16; ++m4) {
            float e0 = __expf(leaky(sv + __shfl(dtot, m4 * 4 + 0)));
            float e1 = __expf(leaky(sv + __shfl(dtot, m4 * 4 + 1)));
            float e2 = __expf(leaky(sv + __shfl(dtot, m4 * 4 + 2)));
            float e3 = __expf(leaky(sv + __shfl(dtot, m4 * 4 + 3)));
            sum += e0 + e1 + e2 + e3;
            #pragma unroll
            for (int q = 0; q < 4; ++q) {
                float4 hv = *reinterpret_cast<const float4*>(&hp2[(wv * 4 + q) * 64 + m4 * 4]);
                acc[q] += e0 * hv.x + e1 * hv.y + e2 * hv.z + e3 * hv.w;
            }
        }
        float rs = frcp(sum);
        #pragma unroll
        for (int q = 0; q < 4; ++q)
            ws2[((size_t)t * 32 + wv * 4 + q) * NTOT + g * 64 + lane] = acc[q] * rs + g2b[wv * 4 + q];
    }
}

// ====================== C: graph LSTM (MFMA, operand-swapped) =============
__global__ __launch_bounds__(512, 1)
void graph_lstm_k(const float* __restrict__ ws2,
                  const float* __restrict__ graph_h0,
                  const float* __restrict__ graph_c0,
                  const float* __restrict__ w_ih_g,
                  const float* __restrict__ w_hh_g,
                  const float* __restrict__ b_ih_g,
                  const float* __restrict__ b_hh_g,
                  float* __restrict__ wsG)
{
    const int g    = blockIdx.x;
    const int lane = threadIdx.x & 63;
    const int wv   = __builtin_amdgcn_readfirstlane((int)(threadIdx.x >> 6));
    const int n    = g * NPED + lane;

    __shared__ __attribute__((aligned(16))) u16 AGh[64 * EAP], AGl[64 * EAP];
    __shared__ float biasg[128];

    const int pfrag = lane & 15, kg8 = (lane >> 4) * 8;
    const int pcol = lane & 15;
    const int jg   = wv * 4 + (lane >> 4);

    short8_t wfhG[2], wflG[2];
    {
        int gp = wv * 16 + pfrag, j = gp >> 2, ty = gp & 3, orig = ty * 32 + j;
        #pragma unroll
        for (int kb = 0; kb < 2; ++kb) {
            short8_t fhG, flG;
            #pragma unroll
            for (int jj = 0; jj < 8; ++jj) {
                int k = kb * 32 + (lane >> 4) * 8 + jj;
                float vG = (k < 32) ? w_ih_g[orig * 32 + k] : w_hh_g[orig * 32 + (k - 32)];
                u16 hG = bhi(vG); fhG[jj] = (short)hG; flG[jj] = (short)bhi(vG - bf2f(hG));
            }
            wfhG[kb] = fhG; wflG[kb] = flG;
        }
    }
    #pragma unroll
    for (int r = 0; r < 4; ++r) {
        int j = wv * 4 + r;
        float vg = graph_h0[(size_t)n * HG_ + j];
        u16 hg = bhi(vg);
        AGh[lane * EAP + 32 + j] = hg;  AGl[lane * EAP + 32 + j] = bhi(vg - bf2f(hg));
    }
    float cG2[4];
    #pragma unroll
    for (int mb = 0; mb < 4; ++mb)
        cG2[mb] = graph_c0[(size_t)(g * 64 + mb * 16 + pcol) * HG_ + jg];
    if (threadIdx.x < 128) biasg[threadIdx.x] = b_ih_g[threadIdx.x] + b_hh_g[threadIdx.x];

    for (int t = 0; t < OBS; ++t) {
        #pragma unroll
        for (int r = 0; r < 4; ++r) {
            int f = wv * 4 + r;
            float v = ws2[((size_t)t * 32 + f) * NTOT + g * 64 + lane];
            u16 h = bhi(v);
            AGh[lane * EAP + f] = h;  AGl[lane * EAP + f] = bhi(v - bf2f(h));
        }
        __syncthreads();   // B1
        float h2G[4];
        {
            f32x4 acc[4];
            #pragma unroll
            for (int mb = 0; mb < 4; ++mb) acc[mb] = (f32x4){0.f, 0.f, 0.f, 0.f};
            #pragma unroll
            for (int kb = 0; kb < 2; ++kb) {
                short8_t ah[4], al[4];
                #pragma unroll
                for (int mb = 0; mb < 4; ++mb) {
                    int off = (mb * 16 + pfrag) * EAP + kb * 32 + kg8;
                    ah[mb] = *(const short8_t*)&AGh[off];
                    al[mb] = *(const short8_t*)&AGl[off];
                }
                #pragma unroll
                for (int mb = 0; mb < 4; ++mb) {
                    acc[mb] = __builtin_amdgcn_mfma_f32_16x16x32_bf16(wfhG[kb], ah[mb], acc[mb], 0, 0, 0);
                    acc[mb] = __builtin_amdgcn_mfma_f32_16x16x32_bf16(wflG[kb], ah[mb], acc[mb], 0, 0, 0);
                    acc[mb] = __builtin_amdgcn_mfma_f32_16x16x32_bf16(wfhG[kb], al[mb], acc[mb], 0, 0, 0);
                }
            }
            const float bI = biasg[jg], bF = biasg[32 + jg], bG = biasg[64 + jg], bO = biasg[96 + jg];
            #pragma unroll
            for (int mb = 0; mb < 4; ++mb) {
                float gi = acc[mb][0] + bI, gf = acc[mb][1] + bF;
                float gg = acc[mb][2] + bG, go = acc[mb][3] + bO;
                float c = sigf(gf) * cG2[mb] + sigf(gi) * tanh_(gg);
                cG2[mb] = c;
                h2G[mb] = sigf(go) * tanh_(c);
            }
        }
        __syncthreads();   // B2
        #pragma unroll
        for (int mb = 0; mb < 4; ++mb) {
            int p = mb * 16 + pcol;
            u16 h = bhi(h2G[mb]);
            AGh[p * EAP + 32 + jg] = h;  AGl[p * EAP + 32 + jg] = bhi(h2G[mb] - bf2f(h));
        }
        if (t == OBS - 1) {
            #pragma unroll
            for (int mb = 0; mb < 4; ++mb)
                wsG[(size_t)jg * NTOT + g * 64 + mb * 16 + pcol] = h2G[mb];
        }
    }
}

// ==== D: decoder (round-15: balanced tiles, 2 barriers/step) ==============
__global__ __launch_bounds__(512, 1)
void stgat_dec(const float* __restrict__ obs,
               const float* __restrict__ zin,
               const float* __restrict__ w_ih_p,
               const float* __restrict__ w_hh_p,
               const float* __restrict__ b_ih_p,
               const float* __restrict__ b_hh_p,
               const float* __restrict__ w_out,
               const float* __restrict__ b_out,
               const float* __restrict__ wsT,
               const float* __restrict__ wsG,
               float* __restrict__ out)
{
    const int g    = blockIdx.x;
    const int lane = threadIdx.x & 63;
    const int wv   = __builtin_amdgcn_readfirstlane((int)(threadIdx.x >> 6));
    const int n    = g * NPED + lane;

    __shared__ __attribute__((aligned(16))) u16 Apk[2 * 64 * AP2 + 16];
    __shared__ __attribute__((aligned(16))) short8_t WloS[18 * 3 * 64];
    __shared__ float red0[512], red1[512];
    u16* AhiA = Apk;
    u16* AhiB = Apk + 64 * AP2;

    const int pfrag = lane & 15, kgrp = (lane >> 4) * 8;
    const int pcol  = lane & 15;
    const int mb2   = wv & 3;
    const int nb2   = 16 + (wv >> 2);

    short8_t wfh[3][3];
    {
        const int col = lane & 15, lb = lane >> 4;
        #pragma unroll
        for (int s = 0; s < 3; ++s) {
            int nb = (s == 2) ? nb2 : (wv + 8 * s);
            int gp = nb * 16 + col;
            int j = gp >> 2, ty = gp & 3;
            int orig = ty * HP_ + j;
            #pragma unroll
            for (int kb = 0; kb < 3; ++kb) {
                short8_t fh, fl;
                #pragma unroll
                for (int jj = 0; jj < 8; ++jj) {
                    int k = kb * 32 + lb * 8 + jj;
                    float v;
                    if (k < 72)       v = w_hh_p[orig * HP_ + k];
                    else if (k == 72) v = w_ih_p[orig * 2 + 0];
                    else if (k == 73) v = w_ih_p[orig * 2 + 1];
                    else if (k == 74) v = b_ih_p[orig] + b_hh_p[orig];
                    else              v = 0.0f;
                    u16 hb = bhi(v);
                    fh[jj] = (short)hb;
                    fl[jj] = (short)bhi(v - bf2f(hb));
                }
                wfh[s][kb] = fh;
                if (s < 2 || (wv & 3) == 0)
                    WloS[(nb * 3 + kb) * 64 + lane] = fl;
            }
        }
    }
    float wo0[3], wo1[3];
    #pragma unroll
    for (int s = 0; s < 3; ++s) {
        int nb = (s == 2) ? nb2 : (wv + 8 * s);
        int j = nb * 4 + (lane >> 4);
        wo0[s] = w_out[j];
        wo1[s] = w_out[HP_ + j];
    }
    const float bo0 = b_out[0], bo1 = b_out[1];

    {
        float px0 = obs[(7 * NTOT + n) * 3 + 0];
        float px1 = obs[(7 * NTOT + n) * 3 + 1];
        #pragma unroll
        for (int kk = 0; kk < 12; ++kk) {
            int k = wv + kk * 8;
            if (k < AP2) {
                float va, vb;
                if (k < 32)       { va = wsT[(size_t)k * NTOT + n];            vb = 0.0f; }
                else if (k < 64)  { va = vb = wsG[(size_t)(k - 32) * NTOT + n]; }
                else if (k < 72)  { va = vb = zin[g * NZ_ + (k - 64)]; }
                else if (k == 72) { va = vb = px0; }
                else if (k == 73) { va = vb = px1; }
                else if (k == 74) { va = vb = 1.0f; }
                else              { va = vb = 0.0f; }
                AhiA[lane * AP2 + k] = bhi(va);
                AhiB[lane * AP2 + k] = bhi(vb);
            }
        }
        if (wv == 0 && lane < 16) Apk[2 * 64 * AP2 + lane] = 0;   // guard
    }
    __syncthreads();

    float cstA[2][4], cstB[2][4], cstA2 = 0.f, cstB2 = 0.f;
    #pragma unroll
    for (int s = 0; s < 2; ++s)
        #pragma unroll
        for (int mb = 0; mb < 4; ++mb) { cstA[s][mb] = 0.0f; cstB[s][mb] = 0.0f; }

    for (int st = 0; st < FUT; ++st) {
        float h2A[2][4], h2B[2][4], h2A2, h2B2;
        // ---- cell A ----
        {
            f32x4 acc[2][4];
            f32x4 acc2 = (f32x4){0.f, 0.f, 0.f, 0.f};
            #pragma unroll
            for (int s = 0; s < 2; ++s)
                #pragma unroll
                for (int mb = 0; mb < 4; ++mb) acc[s][mb] = (f32x4){0.f, 0.f, 0.f, 0.f};
            #pragma unroll
            for (int kb = 0; kb < 3; ++kb) {
                short8_t ah[4];
                #pragma unroll
                for (int mb = 0; mb < 4; ++mb) {
                    int off = (mb * 16 + pfrag) * AP2 + kb * 32 + kgrp;
                    ah[mb] = *(const short8_t*)&AhiA[off];
                }
                #pragma unroll
                for (int s = 0; s < 2; ++s) {
                    int nb = wv + 8 * s;
                    short8_t wl = WloS[(nb * 3 + kb) * 64 + lane];
                    #pragma unroll
                    for (int mb = 0; mb < 4; ++mb) {
                        acc[s][mb] = __builtin_amdgcn_mfma_f32_16x16x32_bf16(wfh[s][kb], ah[mb], acc[s][mb], 0, 0, 0);
                        acc[s][mb] = __builtin_amdgcn_mfma_f32_16x16x32_bf16(wl,         ah[mb], acc[s][mb], 0, 0, 0);
                    }
                }
                short8_t ah2 = *(const short8_t*)&AhiA[(mb2 * 16 + pfrag) * AP2 + kb * 32 + kgrp];
                short8_t wl2 = WloS[(nb2 * 3 + kb) * 64 + lane];
                acc2 = __builtin_amdgcn_mfma_f32_16x16x32_bf16(wfh[2][kb], ah2, acc2, 0, 0, 0);
                acc2 = __builtin_amdgcn_mfma_f32_16x16x32_bf16(wl2,        ah2, acc2, 0, 0, 0);
            }
            #pragma unroll
            for (int s = 0; s < 2; ++s)
                #pragma unroll
                for (int mb = 0; mb < 4; ++mb) {
                    float gi = acc[s][mb][0], gf = acc[s][mb][1];
                    float gg = acc[s][mb][2], go = acc[s][mb][3];
                    float c = sigf(gf) * cstA[s][mb] + sigf(gi) * tanh_(gg);
                    cstA[s][mb] = c;
                    h2A[s][mb] = sigf(go) * tanh_(c);
                }
            {
                float gi = acc2[0], gf = acc2[1], gg = acc2[2], go = acc2[3];
                float c = sigf(gf) * cstA2 + sigf(gi) * tanh_(gg);
                cstA2 = c;
                h2A2 = sigf(go) * tanh_(c);
            }
        }
        // ---- cell B ----
        {
            f32x4 acc[2][4];
            f32x4 acc2 = (f32x4){0.f, 0.f, 0.f, 0.f};
            #pragma unroll
            for (int s = 0; s < 2; ++s)
                #pragma unroll
                for (int mb = 0; mb < 4; ++mb) acc[s][mb] = (f32x4){0.f, 0.f, 0.f, 0.f};
            #pragma unroll
            for (int kb = 0; kb < 3; ++kb) {
                short8_t bh[4];
                #pragma unroll
                for (int mb = 0; mb < 4; ++mb) {
                    int off = (mb * 16 + pfrag) * AP2 + kb * 32 + kgrp;
                    bh[mb] = *(const short8_t*)&AhiB[off];
                }
                #pragma unroll
                for (int s = 0; s < 2; ++s) {
                    int nb = wv + 8 * s;
                    short8_t wl = WloS[(nb * 3 + kb) * 64 + lane];
                    #pragma unroll
                    for (int mb = 0; mb < 4; ++mb) {
                        acc[s][mb] = __builtin_amdgcn_mfma_f32_16x16x32_bf16(wfh[s][kb], bh[mb], acc[s][mb], 0, 0, 0);
                        acc[s][mb] = __builtin_amdgcn_mfma_f32_16x16x32_bf16(wl,         bh[mb], acc[s][mb], 0, 0, 0);
                    }
                }
                short8_t bh2 = *(const short8_t*)&AhiB[(mb2 * 16 + pfrag) * AP2 + kb * 32 + kgrp];
                short8_t wl2 = WloS[(nb2 * 3 + kb) * 64 + lane];
                acc2 = __builtin_amdgcn_mfma_f32_16x16x32_bf16(wfh[2][kb], bh2, acc2, 0, 0, 0);
                acc2 = __builtin_amdgcn_mfma_f32_16x16x32_bf16(wl2,        bh2, acc2, 0, 0, 0);
            }
            #pragma unroll
            for (int s = 0; s < 2; ++s)
                #pragma unroll
                for (int mb = 0; mb < 4; ++mb) {
                    float gi = acc[s][mb][0], gf = acc[s][mb][1];
                    float gg = acc[s][mb][2], go = acc[s][mb][3];
                    float c = sigf(gf) * cstB[s][mb] + sigf(gi) * tanh_(gg);
                    cstB[s][mb] = c;
                    h2B[s][mb] = sigf(go) * tanh_(c);
                }
            {
                float gi = acc2[0], gf = acc2[1], gg = acc2[2], go = acc2[3];
                float c = sigf(gf) * cstB2 + sigf(gi) * tanh_(gg);
                cstB2 = c;
                h2B2 = sigf(go) * tanh_(c);
            }
        }
        // ---- register partial dot + j-reduction + PRE-B1 red stash ----
        float po0[4] = {0.f, 0.f, 0.f, 0.f}, po1[4] = {0.f, 0.f, 0.f, 0.f};
        #pragma unroll
        for (int s = 0; s < 2; ++s)
            #pragma unroll
            for (int mb = 0; mb < 4; ++mb) {
                float dh = h2A[s][mb] - h2B[s][mb];
                po0[mb] += wo0[s] * dh;
                po1[mb] += wo1[s] * dh;
            }
        {
            float dh2 = h2A2 - h2B2;
            float c0 = wo0[2] * dh2, c1 = wo1[2] * dh2;
            #pragma unroll
            for (int mb = 0; mb < 4; ++mb) {
                po0[mb] += (mb == mb2) ? c0 : 0.0f;
                po1[mb] += (mb == mb2) ? c1 : 0.0f;
            }
        }
        #pragma unroll
        for (int mb = 0; mb < 4; ++mb) {
            po0[mb] += __shfl_xor(po0[mb], 16);  po0[mb] += __shfl_xor(po0[mb], 32);
            po1[mb] += __shfl_xor(po1[mb], 16);  po1[mb] += __shfl_xor(po1[mb], 32);
        }
        if ((lane >> 4) == 0) {
            #pragma unroll
            for (int mb = 0; mb < 4; ++mb) {
                red0[wv * 64 + mb * 16 + lane] = po0[mb];
                red1[wv * 64 + mb * 16 + lane] = po1[mb];
            }
        }
        __syncthreads();   // B1: GEMM reads done; red visible
        #pragma unroll
        for (int s = 0; s < 2; ++s) {
            int j = (wv + 8 * s) * 4 + (lane >> 4);
            #pragma unroll
            for (int mb = 0; mb < 4; ++mb) {
                int p = mb * 16 + pcol;
                AhiA[p * AP2 + j] = bhi(h2A[s][mb]);
                AhiB[p * AP2 + j] = bhi(h2B[s][mb]);
            }
        }
        {
            int j2 = nb2 * 4 + (lane >> 4);
            int p2 = mb2 * 16 + pcol;
            AhiA[p2 * AP2 + j2] = bhi(h2A2);
            AhiB[p2 * AP2 + j2] = bhi(h2B2);
        }
        if (wv == 0) {
            float o0 = bo0, o1 = bo1;
            #pragma unroll
            for (int w = 0; w < 8; ++w) { o0 += red0[w * 64 + lane]; o1 += red1[w * 64 + lane]; }
            *reinterpret_cast<float2*>(&out[(size_t)(st * NTOT + n) * 2]) = make_float2(o0, o1);
            u16 h0_ = bhi(o0);
            u16 h1  = bhi(o1);
            AhiA[lane * AP2 + 72] = h0_;  AhiB[lane * AP2 + 72] = h0_;
            AhiA[lane * AP2 + 73] = h1;   AhiB[lane * AP2 + 73] = h1;
        }
        __syncthreads();   // B2: h2 + px visible
    }
}

extern "C" void kernel_launch(void* const* d_in, const int* in_sizes, int n_in,
                              void* d_out, int out_size, void* d_ws, size_t ws_size,
                              hipStream_t stream) {
    (void)in_sizes; (void)n_in; (void)out_size; (void)ws_size;
    const size_t NF = (size_t)OBS * 32 * NTOT;
    float* ws1 = (float*)d_ws;
    float* ws2 = ws1 + NF;
    float* wsT = ws2 + NF;
    float* wsG = wsT + (size_t)32 * NTOT;

    traj_lstm_k<<<dim3(NGR), dim3(512), 0, stream>>>(
        (const float*)d_in[0], (const float*)d_in[2], (const float*)d_in[3],
        (const float*)d_in[6], (const float*)d_in[7], (const float*)d_in[8], (const float*)d_in[9],
        ws1, wsT);

    gat_k<<<dim3(OBS * NGR), dim3(512), 0, stream>>>(
        ws1,
        (const float*)d_in[10], (const float*)d_in[11], (const float*)d_in[12], (const float*)d_in[13],
        (const float*)d_in[14], (const float*)d_in[15], (const float*)d_in[16], (const float*)d_in[17],
        ws2);

    graph_lstm_k<<<dim3(NGR), dim3(512), 0, stream>>>(
        ws2, (const float*)d_in[4], (const float*)d_in[5],
        (const float*)d_in[18], (const float*)d_in[19], (const float*)d_in[20], (const float*)d_in[21],
        wsG);

    stgat_dec<<<dim3(NGR), dim3(512), 0, stream>>>(
        (const float*)d_in[0], (const float*)d_in[1],
        (const float*)d_in[22], (const float*)d_in[23],
        (const float*)d_in[24], (const float*)d_in[25],
        (const float*)d_in[26], (const float*)d_in[27],
        wsT, wsG, (float*)d_out);
}